// Round 10
// baseline (326.943 us; speedup 1.0000x reference)
//
#include <hip/hip_runtime.h>
#include <math.h>

#define NROW 8192
#define DDIM 128
#define CAP 16384
#define NDIAG 8192       // entries [0,8192) are the implicit diagonal (i==j==e)
#define NITERS 100
#define NWARM 6
#define AC (1.0f / 8192.0f)

struct Entry { int i, j; float s, t; };

// ws layout (bytes):
// 0       : x2   float[NROW]
// 32768   : y2   float[NROW]
// 65536   : x2h  float[NROW]     partial (32-dim) norms
// 98304   : y2h  float[NROW]
// 131072  : counts int[8]        { [0..2]=list counts (start NDIAG), [3..5]=off-diag active }
// 131104  : minx32 uint[64]      per-128-row-tile min of x2h
// 131360  : miny32 uint[64]
// 131616  : accum double[3][264] { [0..4]=Su,Sv,Sux2,Svy2,Ssp [5]=R [6]=bu [7]=bv [8..]=P,Q }
// 137952  : lists Entry[3][CAP]  (slots [0,8192) unused; scan appends at >=8192)
// 924384  : X32 ushort[NROW*32]  bf16 of first 32 dims
// 1448672 : Y32 ushort[NROW*32]
// 1972960 : sdiag float[3][NROW]
// 2071264 : tdiag float[3][NROW]
// 2169568 : u_g  float[3][NROW]
// 2267872 : v_g  float[3][NROW]  -> total 2366176

typedef __attribute__((ext_vector_type(8))) short frag_ab;   // 8 bf16
typedef __attribute__((ext_vector_type(4))) float frag_cd;   // 4 fp32

__device__ inline unsigned short f2bf(float f) {
    unsigned u = __float_as_uint(f);
    return (unsigned short)((u + 0x7FFFu + ((u >> 16) & 1u)) >> 16);  // RN-even
}

// one block per 128-row tile (b<64: X, else Y). Computes full+partial norms,
// bf16 compaction, per-tile partial-norm min (block-local). Block 0 also
// initializes counts/accum. Replaces init_k + old norms_k.
__global__ __launch_bounds__(256) void norms2_k(const float* __restrict__ X,
                                                const float* __restrict__ Y,
                                                float* __restrict__ x2, float* __restrict__ y2,
                                                float* __restrict__ x2h, float* __restrict__ y2h,
                                                unsigned* __restrict__ minx32,
                                                unsigned* __restrict__ miny32,
                                                unsigned short* __restrict__ X32,
                                                unsigned short* __restrict__ Y32,
                                                int* counts, double* accum) {
    int b = blockIdx.x;
    bool isX = b < 64;
    int tile = isX ? b : b - 64;
    const float* M = isX ? X : Y;
    float* out = isX ? x2 : y2;
    float* outh = isX ? x2h : y2h;
    unsigned short* Mb = isX ? X32 : Y32;
    int t = threadIdx.x, w = t >> 6, lane = t & 63;
    float mloc = 1e30f;
    int rbase = tile * 128 + w * 32;
    for (int k = 0; k < 32; k++) {
        int r = rbase + k;
        float2 v = *(const float2*)(M + (size_t)r * DDIM + lane * 2);
        if (lane < 16) {
            unsigned pk = (unsigned)f2bf(v.x) | ((unsigned)f2bf(v.y) << 16);
            *(unsigned*)(Mb + (size_t)r * 32 + lane * 2) = pk;
        }
        float e = v.x * v.x + v.y * v.y;
        float s = e, ph = (lane < 16) ? e : 0.f;
        for (int o = 32; o; o >>= 1) { s += __shfl_down(s, o, 64); ph += __shfl_down(ph, o, 64); }
        if (lane == 0) { out[r] = s; outh[r] = ph; mloc = fminf(mloc, ph); }
    }
    __shared__ float mred[4];
    if (lane == 0) mred[w] = mloc;
    __syncthreads();
    if (t == 0) {
        float m = fminf(fminf(mred[0], mred[1]), fminf(mred[2], mred[3]));
        (isX ? minx32 : miny32)[tile] = __float_as_uint(m);   // ph>=0: uint order == float order
    }
    if (b == 0) {
        if (t < 3) counts[t] = NDIAG;
        else if (t < 8) counts[t] = 0;
        for (int idx = t; idx < 3 * 264; idx += 256) accum[idx] = 0.0;
    }
}

// LDS-free 32-dim MFMA prescan, 8 j-tiles per block (dispatch-amortized).
// C32 = x2h[i]+y2h[j]-2*dot32 is an exact lower bound on C.
__global__ __launch_bounds__(256) void scan5_k(const unsigned short* __restrict__ X32,
                                               const unsigned short* __restrict__ Y32,
                                               const float* __restrict__ x2h,
                                               const float* __restrict__ y2h,
                                               const unsigned* __restrict__ minx32,
                                               const unsigned* __restrict__ miny32,
                                               int* counts, Entry* lists) {
    int p = blockIdx.z, bx = blockIdx.x;
    int jt_begin = blockIdx.y * 8, jt_end = jt_begin + 8;
    if (p && jt_end <= bx) return;            // symmetric pairs: whole chunk below diagonal
    const unsigned short* Ab = (p == 2) ? Y32 : X32;
    const unsigned short* Bb = (p == 0) ? Y32 : ((p == 1) ? X32 : Y32);
    const float* na = (p == 2) ? y2h : x2h;
    const float* nb = (p == 0) ? y2h : ((p == 1) ? x2h : y2h);
    const unsigned* mAarr = (p == 2) ? miny32 : minx32;
    const unsigned* mBarr = (p == 0) ? miny32 : ((p == 1) ? minx32 : miny32);
    int i0 = bx * 128;
    int t = threadIdx.x, w = t >> 6, lane = t & 63, lm = lane & 15, quad = lane >> 4;
    int wr = (w & 1) * 64, wc = (w >> 1) * 64;

    frag_ab a[4];
    #pragma unroll
    for (int rt = 0; rt < 4; rt++)
        a[rt] = *(const frag_ab*)(Ab + (size_t)(i0 + wr + rt * 16 + lm) * 32 + quad * 8);
    float mA = __uint_as_float(mAarr[bx]);
    Entry* list = lists + (size_t)p * CAP;

    int jts = (p && bx > jt_begin) ? bx : jt_begin;
    for (int jt = jts; jt < jt_end; jt++) {
        int j0 = jt * 128;
        frag_ab bf[4];
        #pragma unroll
        for (int ct = 0; ct < 4; ct++)
            bf[ct] = *(const frag_ab*)(Bb + (size_t)(j0 + wc + ct * 16 + lm) * 32 + quad * 8);
        frag_cd acc[4][4];
        #pragma unroll
        for (int rt = 0; rt < 4; rt++)
            #pragma unroll
            for (int ct = 0; ct < 4; ct++)
                acc[rt][ct] = __builtin_amdgcn_mfma_f32_16x16x32_bf16(a[rt], bf[ct],
                              (frag_cd){0.f, 0.f, 0.f, 0.f}, 0, 0, 0);
        float mB = __uint_as_float(mBarr[jt]);
        float thr = 0.5f * (mA + mB - 2.0f);
        #pragma unroll
        for (int rt = 0; rt < 4; rt++) {
            #pragma unroll
            for (int ct = 0; ct < 4; ct++) {
                frag_cd A4 = acc[rt][ct];
                float m4 = fmaxf(fmaxf(A4[0], A4[1]), fmaxf(A4[2], A4[3]));
                if (__any(m4 > thr)) {
                    int j = j0 + wc + ct * 16 + lm;
                    float yj = nb[j];
                    #pragma unroll
                    for (int reg = 0; reg < 4; reg++) {
                        int i = i0 + wr + rt * 16 + quad * 4 + reg;
                        float Ct = na[i] + yj - 2.f * A4[reg];
                        if (Ct < 2.0f && i != j) {
                            if (p == 0) {
                                int idx = atomicAdd(&counts[0], 1);
                                if (idx < CAP) { Entry e; e.i = i; e.j = j; e.s = 0.f; e.t = 0.f; list[idx] = e; }
                            } else if (i < j) {
                                int idx = atomicAdd(&counts[p], 2);
                                if (idx < CAP) { Entry e; e.i = i; e.j = j; e.s = 0.f; e.t = 0.f; list[idx] = e; }
                                if (idx + 1 < CAP) { Entry e; e.i = j; e.j = i; e.s = 0.f; e.t = 0.f; list[idx + 1] = e; }
                            }
                        }
                    }
                }
            }
        }
    }
}

// exact full-128-dim fp32 distance. e<NDIAG is the implicit diagonal (i=j=e) ->
// sdiag/tdiag; e>=NDIAG from list -> list.s/.t + rescnt. 192 blocks, stride loop.
__global__ __launch_bounds__(256) void exact2_k(const float* __restrict__ X,
                                                const float* __restrict__ Y,
                                                const float* __restrict__ x2,
                                                const float* __restrict__ y2,
                                                const int* counts, Entry* lists,
                                                float* __restrict__ sdiag,
                                                float* __restrict__ tdiag,
                                                int* rescnt) {
    int p = blockIdx.y;
    const float* A = (p == 2) ? Y : X;
    const float* B = (p == 0) ? Y : ((p == 1) ? X : Y);
    const float* na = (p == 2) ? y2 : x2;
    const float* nb = (p == 0) ? y2 : ((p == 1) ? x2 : y2);
    int cnt = counts[p]; if (cnt > CAP) cnt = CAP;
    Entry* list = lists + (size_t)p * CAP;
    int w = (blockIdx.x * 256 + threadIdx.x) >> 6;   // 64 blocks * 4 waves = 256 slots
    int lane = threadIdx.x & 63;
    for (int e = w; e < cnt; e += 256) {
        int i, j;
        if (e < NDIAG) { i = e; j = e; }
        else { i = list[e].i; j = list[e].j; }
        const float* ar = A + (size_t)i * DDIM;
        const float* br = B + (size_t)j * DDIM;
        float dot = ar[lane] * br[lane] + ar[lane + 64] * br[lane + 64];
        for (int o = 32; o; o >>= 1) dot += __shfl_down(dot, o, 64);
        if (lane == 0) {
            float raw = na[i] + nb[j] - 2.0f * dot;
            float C = fmaxf(raw, 0.0f);
            float sc = fmaxf(-C * 100.0f, -50.0f);
            float K = fmaxf(expf(sc), 1e-8f);
            float s = K - 1e-8f;
            float tt = (raw >= 0.f) ? s * C : (-1e-8f) * raw;   // exactly 0 when s==0
            if (e < NDIAG) { sdiag[p * NROW + i] = s; tdiag[p * NROW + i] = tt; }
            else {
                list[e].s = s; list[e].t = tt;
                if (s != 0.f || tt != 0.f) atomicAdd(&rescnt[p], 1);
            }
        }
    }
}

// Warm Sinkhorn: NWARM exact coupled iterations, then freeze bases (sub-ulp drift);
// bit-exact early exit (period 1/2, parity-corrected) -> R=0. Fallback: full scatter.
__global__ __launch_bounds__(1024, 1) void sink2_k(const int* counts,
                                                   const Entry* __restrict__ lists,
                                                   const float* __restrict__ sdiag,
                                                   float* __restrict__ u_g,
                                                   float* __restrict__ v_g,
                                                   double* accum) {
    int p = blockIdx.x;
    const Entry* list = lists + (size_t)p * CAP;
    int cnt = counts[p]; if (cnt > CAP) cnt = CAP;
    int nres = counts[3 + p];
    double* acc = accum + (size_t)p * 264;
    float* up = u_g + (size_t)p * NROW;
    float* vp = v_g + (size_t)p * NROW;

    __shared__ float u_s[NROW];   // fallback only
    __shared__ float v_s[NROW];
    __shared__ float redS[2][16];
    __shared__ unsigned redC[16];
    int t = threadIdx.x;
    int wid = t >> 6, lane = t & 63;

    if (nres == 0) {
        float vk[8], uk[8], sk[8];
        unsigned pv2[8];
        #pragma unroll
        for (int k = 0; k < 8; k++) {
            sk[k] = sdiag[p * NROW + t + 1024 * k];
            vk[k] = 1.0f; uk[k] = AC; pv2[k] = 0xFFFFFFFFu;
        }
        unsigned flags = 3u;
        int par = 0, last = 0, done = 0;
        float bu_last = 0.f;
        for (int it = 0; it < NWARM; it++) {
            float s = 0.f;
            #pragma unroll
            for (int k = 0; k < 8; k++) s += vk[k];
            for (int o = 32; o; o >>= 1) s += __shfl_down(s, o, 64);
            if (lane == 0) { redS[par][wid] = s; redC[wid] = flags; }
            __syncthreads();
            float sumv = 0.f; unsigned anyf = 0;
            #pragma unroll
            for (int w2 = 0; w2 < 16; w2++) { sumv += redS[par][w2]; anyf |= redC[w2]; }
            par ^= 1;
            if (it > 0) {
                if (!(anyf & 1)) { done = 1; break; }
                if (!(anyf & 2)) {
                    if (((NITERS - it) & 1) == 0) { done = 1; break; }
                    last = 1;
                }
            }
            float base = 1e-8f * sumv;
            #pragma unroll
            for (int k = 0; k < 8; k++) {
                float kv = fmaxf(base + sk[k] * vk[k], 1e-8f);
                uk[k] = AC * __builtin_amdgcn_rcpf(kv);
            }
            s = 0.f;
            #pragma unroll
            for (int k = 0; k < 8; k++) s += uk[k];
            for (int o = 32; o; o >>= 1) s += __shfl_down(s, o, 64);
            if (lane == 0) redS[par][wid] = s;
            __syncthreads();
            float sumu = 0.f;
            #pragma unroll
            for (int w2 = 0; w2 < 16; w2++) sumu += redS[par][w2];
            par ^= 1;
            base = 1e-8f * sumu;
            bu_last = base;
            unsigned d1 = 0, d2 = 0;
            #pragma unroll
            for (int k = 0; k < 8; k++) {
                float kv = fmaxf(base + sk[k] * uk[k], 1e-8f);
                float nv = AC * __builtin_amdgcn_rcpf(kv);
                unsigned nb_ = __float_as_uint(nv);
                d1 |= nb_ ^ __float_as_uint(vk[k]);
                d2 |= nb_ ^ pv2[k];
                pv2[k] = __float_as_uint(vk[k]);
                vk[k] = nv;
            }
            flags = (__any(d1 != 0) ? 1u : 0u) | (__any(d2 != 0) ? 2u : 0u);
            if (last) { done = 1; break; }
        }
        float bv_f = 0.f;
        int R = 0;
        if (!done) {
            float s = 0.f;
            #pragma unroll
            for (int k = 0; k < 8; k++) s += vk[k];
            for (int o = 32; o; o >>= 1) s += __shfl_down(s, o, 64);
            if (lane == 0) redS[par][wid] = s;
            __syncthreads();
            float sumv = 0.f;
            #pragma unroll
            for (int w2 = 0; w2 < 16; w2++) sumv += redS[par][w2];
            bv_f = 1e-8f * sumv;
            R = NITERS - NWARM;
        }
        #pragma unroll
        for (int k = 0; k < 8; k++) {
            int i = t + 1024 * k;
            up[i] = uk[k]; vp[i] = vk[k];
        }
        if (t == 0) { acc[5] = (double)R; acc[6] = (double)bu_last; acc[7] = (double)bv_f; }
    } else {
        // fallback: general sparse scatter (implicit diag + list), full 100 iterations
        for (int i = t; i < NROW; i += 1024) { u_s[i] = 1.0f; v_s[i] = 1.0f; }
        __syncthreads();
        for (int it = 0; it < NITERS; it++) {
            {
                float sv = 0.f;
                for (int i = t; i < NROW; i += 1024) sv += v_s[i];
                for (int o = 32; o; o >>= 1) sv += __shfl_down(sv, o, 64);
                if (lane == 0) u_s[wid] = sv;
                __syncthreads();
                if (t < 64) {
                    float s2 = (t < 16) ? u_s[t] : 0.f;
                    for (int o = 8; o; o >>= 1) s2 += __shfl_down(s2, o, 64);
                    if (t == 0) u_s[0] = s2;
                }
                __syncthreads();
                float sum_v = u_s[0];
                __syncthreads();
                for (int i = t; i < NROW; i += 1024) u_s[i] = 1e-8f * sum_v;
                __syncthreads();
                for (int e = t; e < cnt; e += 1024) {
                    int ei, ej; float es;
                    if (e < NDIAG) { ei = e; ej = e; es = sdiag[p * NROW + e]; }
                    else { ei = list[e].i; ej = list[e].j; es = list[e].s; }
                    atomicAdd(&u_s[ei], es * v_s[ej]);
                }
                __syncthreads();
                for (int i = t; i < NROW; i += 1024) u_s[i] = AC / fmaxf(u_s[i], 1e-8f);
                __syncthreads();
            }
            {
                float su = 0.f;
                for (int i = t; i < NROW; i += 1024) su += u_s[i];
                for (int o = 32; o; o >>= 1) su += __shfl_down(su, o, 64);
                if (lane == 0) v_s[wid] = su;
                __syncthreads();
                if (t < 64) {
                    float s2 = (t < 16) ? v_s[t] : 0.f;
                    for (int o = 8; o; o >>= 1) s2 += __shfl_down(s2, o, 64);
                    if (t == 0) v_s[0] = s2;
                }
                __syncthreads();
                float sum_u = v_s[0];
                __syncthreads();
                for (int i = t; i < NROW; i += 1024) v_s[i] = 1e-8f * sum_u;
                __syncthreads();
                for (int e = t; e < cnt; e += 1024) {
                    int ei, ej; float es;
                    if (e < NDIAG) { ei = e; ej = e; es = sdiag[p * NROW + e]; }
                    else { ei = list[e].i; ej = list[e].j; es = list[e].s; }
                    atomicAdd(&v_s[ej], es * u_s[ei]);
                }
                __syncthreads();
                for (int i = t; i < NROW; i += 1024) v_s[i] = AC / fmaxf(v_s[i], 1e-8f);
                __syncthreads();
            }
        }
        for (int i = t; i < NROW; i += 1024) { up[i] = u_s[i]; vp[i] = v_s[i]; }
        if (t == 0) { acc[5] = 0.0; acc[6] = 0.0; acc[7] = 0.0; }
    }
}

// fused epilogue, all 3 pairs in one pass: frozen-base iters per p, scalar sums,
// then P/Q with X and Y each read ONCE (3 weighted sums per row).
__global__ __launch_bounds__(256) void epi2_k(const float* __restrict__ X,
                                              const float* __restrict__ Y,
                                              const float* __restrict__ x2,
                                              const float* __restrict__ y2,
                                              const float* __restrict__ u_g,
                                              const float* __restrict__ v_g,
                                              const float* __restrict__ sdiag,
                                              const float* __restrict__ tdiag,
                                              double* accum) {
    int t = threadIdx.x, lane = t & 63;
    int rbase = blockIdx.x * 256;
    int r = rbase + t;
    __shared__ float uf[3][256], vf[3][256];
    for (int p = 0; p < 3; p++) {
        double* acc = accum + (size_t)p * 264;
        int R = (int)acc[5];
        float bu = (float)acc[6], bv = (float)acc[7];
        float s = sdiag[p * NROW + r];
        float u = u_g[p * NROW + r], v = v_g[p * NROW + r];
        for (int k = 0; k < R; k++) {
            u = AC * __builtin_amdgcn_rcpf(fmaxf(bv + s * v, 1e-8f));
            v = AC * __builtin_amdgcn_rcpf(fmaxf(bu + s * u, 1e-8f));
        }
        uf[p][t] = u; vf[p][t] = v;
        const float* na = (p == 2) ? y2 : x2;
        const float* nb = (p == 0) ? y2 : ((p == 1) ? x2 : y2);
        double a0 = u, a1 = v, a2 = (double)u * na[r], a3 = (double)v * nb[r];
        double a4 = (double)u * (double)v * (double)tdiag[p * NROW + r];
        for (int o = 32; o; o >>= 1) {
            a0 += __shfl_down(a0, o, 64); a1 += __shfl_down(a1, o, 64);
            a2 += __shfl_down(a2, o, 64); a3 += __shfl_down(a3, o, 64);
            a4 += __shfl_down(a4, o, 64);
        }
        if (lane == 0) {
            atomicAdd(&acc[0], a0); atomicAdd(&acc[1], a1);
            atomicAdd(&acc[2], a2); atomicAdd(&acc[3], a3);
            atomicAdd(&acc[4], a4);
        }
    }
    __syncthreads();
    int dq = (t & 31) * 4, g = t >> 5;
    {   // X pass: weights u0 -> P0, u1 -> P1, v1 -> Q1
        double s0[4] = {0,0,0,0}, s1[4] = {0,0,0,0}, s2[4] = {0,0,0,0};
        for (int k = 0; k < 32; k++) {
            int lr = g + 8 * k, rr = rbase + lr;
            float4 xv = *(const float4*)(X + (size_t)rr * DDIM + dq);
            double w0 = uf[0][lr], w1 = uf[1][lr], w2 = vf[1][lr];
            s0[0] += w0 * xv.x; s0[1] += w0 * xv.y; s0[2] += w0 * xv.z; s0[3] += w0 * xv.w;
            s1[0] += w1 * xv.x; s1[1] += w1 * xv.y; s1[2] += w1 * xv.z; s1[3] += w1 * xv.w;
            s2[0] += w2 * xv.x; s2[1] += w2 * xv.y; s2[2] += w2 * xv.z; s2[3] += w2 * xv.w;
        }
        #pragma unroll
        for (int m = 0; m < 4; m++) {
            atomicAdd(&accum[0 * 264 + 8 + dq + m], s0[m]);
            atomicAdd(&accum[1 * 264 + 8 + dq + m], s1[m]);
            atomicAdd(&accum[1 * 264 + 136 + dq + m], s2[m]);
        }
    }
    {   // Y pass: weights v0 -> Q0, u2 -> P2, v2 -> Q2
        double s0[4] = {0,0,0,0}, s1[4] = {0,0,0,0}, s2[4] = {0,0,0,0};
        for (int k = 0; k < 32; k++) {
            int lr = g + 8 * k, rr = rbase + lr;
            float4 yv = *(const float4*)(Y + (size_t)rr * DDIM + dq);
            double w0 = vf[0][lr], w1 = uf[2][lr], w2 = vf[2][lr];
            s0[0] += w0 * yv.x; s0[1] += w0 * yv.y; s0[2] += w0 * yv.z; s0[3] += w0 * yv.w;
            s1[0] += w1 * yv.x; s1[1] += w1 * yv.y; s1[2] += w1 * yv.z; s1[3] += w1 * yv.w;
            s2[0] += w2 * yv.x; s2[1] += w2 * yv.y; s2[2] += w2 * yv.z; s2[3] += w2 * yv.w;
        }
        #pragma unroll
        for (int m = 0; m < 4; m++) {
            atomicAdd(&accum[0 * 264 + 136 + dq + m], s0[m]);
            atomicAdd(&accum[2 * 264 + 8 + dq + m], s1[m]);
            atomicAdd(&accum[2 * 264 + 136 + dq + m], s2[m]);
        }
    }
}

// off-diag sparse correction (nonzero only in fallback, where u_g/v_g are final;
// in fast path all off-diag t==0) + final combine.
__global__ void combine2_k(const int* counts, const Entry* __restrict__ lists,
                           const float* __restrict__ u_g, const float* __restrict__ v_g,
                           const double* __restrict__ accum, float* __restrict__ out) {
    int t = threadIdx.x, lane = t & 63, wv = t >> 6;   // 256 threads
    __shared__ double red[3][4];
    __shared__ double costs[3];
    for (int p = 0; p < 3; p++) {
        int cnt = counts[p]; if (cnt > CAP) cnt = CAP;
        const Entry* list = lists + (size_t)p * CAP;
        const float* up = u_g + (size_t)p * NROW;
        const float* vp = v_g + (size_t)p * NROW;
        double sp = 0.0;
        for (int e = NDIAG + t; e < cnt; e += 256) {
            Entry en = list[e];
            if (en.t != 0.f) sp += (double)up[en.i] * (double)vp[en.j] * (double)en.t;
        }
        for (int o = 32; o; o >>= 1) sp += __shfl_down(sp, o, 64);
        if (lane == 0) red[p][wv] = sp;
    }
    __syncthreads();
    if (t < 64) {
        for (int p = 0; p < 3; p++) {
            const double* acc = accum + (size_t)p * 264;
            double part = acc[8 + t] * acc[136 + t] + acc[8 + 64 + t] * acc[136 + 64 + t];
            for (int o = 32; o; o >>= 1) part += __shfl_down(part, o, 64);
            if (t == 0) {
                double spo = red[p][0] + red[p][1] + red[p][2] + red[p][3];
                double F = acc[2] * acc[1] + acc[0] * acc[3] - 2.0 * part;
                double c = 1e-8 * F + acc[4] + spo;
                costs[p] = (c > 0.0) ? c : 0.0;
            }
        }
        if (t == 0) {
            double dv = costs[0] - 0.5 * (costs[1] + costs[2]);
            dv = fmin(fmax(dv, 0.0), 10000.0);
            out[0] = (float)dv;
        }
    }
}

extern "C" void kernel_launch(void* const* d_in, const int* in_sizes, int n_in,
                              void* d_out, int out_size, void* d_ws, size_t ws_size,
                              hipStream_t stream) {
    const float* X = (const float*)d_in[0];
    const float* Y = (const float*)d_in[1];
    float* out = (float*)d_out;
    char* ws = (char*)d_ws;
    float* x2 = (float*)ws;
    float* y2 = (float*)(ws + 32768);
    float* x2h = (float*)(ws + 65536);
    float* y2h = (float*)(ws + 98304);
    int* counts = (int*)(ws + 131072);
    unsigned* minx32 = (unsigned*)(ws + 131104);
    unsigned* miny32 = (unsigned*)(ws + 131360);
    double* accum = (double*)(ws + 131616);
    Entry* lists = (Entry*)(ws + 137952);
    unsigned short* X32 = (unsigned short*)(ws + 924384);
    unsigned short* Y32 = (unsigned short*)(ws + 1448672);
    float* sdiag = (float*)(ws + 1972960);
    float* tdiag = (float*)(ws + 2071264);
    float* u_g = (float*)(ws + 2169568);
    float* v_g = (float*)(ws + 2267872);

    norms2_k<<<128, 256, 0, stream>>>(X, Y, x2, y2, x2h, y2h, minx32, miny32, X32, Y32, counts, accum);
    scan5_k<<<dim3(64, 8, 3), 256, 0, stream>>>(X32, Y32, x2h, y2h, minx32, miny32, counts, lists);
    exact2_k<<<dim3(64, 3), 256, 0, stream>>>(X, Y, x2, y2, counts, lists, sdiag, tdiag, counts + 3);
    sink2_k<<<3, 1024, 0, stream>>>(counts, lists, sdiag, u_g, v_g, accum);
    epi2_k<<<32, 256, 0, stream>>>(X, Y, x2, y2, u_g, v_g, sdiag, tdiag, accum);
    combine2_k<<<1, 256, 0, stream>>>(counts, lists, u_g, v_g, accum, out);
}